// Round 3
// baseline (369.672 us; speedup 1.0000x reference)
//
#include <hip/hip_runtime.h>
#include <math.h>

#define LEN   2048
#define EDIM  512
#define NB    16
#define NH    8
#define HD    64
#define TOPK  7
#define LBLK  128              // l's per topk block
#define VROWS (LBLK + 64)      // staged V rows: window is [l-63, l]

__device__ inline float2 cmul(float2 a, float2 b) {
    return make_float2(a.x * b.x - a.y * b.y, a.x * b.y + a.y * b.x);
}
__device__ inline float2 cadd(float2 a, float2 b) { return make_float2(a.x + b.x, a.y + b.y); }
__device__ inline float2 csub(float2 a, float2 b) { return make_float2(a.x - b.x, a.y - b.y); }
// XOR swizzle: conflict-free for strides 256/32/4/1 AND keeps array size 2048
// (32768 B for A+Bs -> exactly 5 blocks/CU; the old +1-per-32 pad was 33792 B -> 4).
__device__ inline int sw(int i) { return i ^ ((i >> 5) & 15); }

// K0: (B, L, E) -> (B*E, L) transpose for q and k. 64x64 tiles, float4 global
// accesses both directions (16 B/lane); scalar LDS staging (2-way/4-way, free-ish).
__global__ __launch_bounds__(256) void transpose_qk(const float* __restrict__ q,
                                                    const float* __restrict__ k,
                                                    float* __restrict__ qT,
                                                    float* __restrict__ kT) {
    __shared__ float tile[64][65];
    int b  = blockIdx.z;
    int e0 = blockIdx.x * 64;
    int t0 = blockIdx.y * 64;
    int tid = threadIdx.x;
    int tr = tid >> 4, cx = tid & 15;   // load: 16 rows x 16 float4-cols
    int er = tid >> 2, tg = tid & 3;    // store: 64 rows x 4 float4-segs
    const float* qb = q + (size_t)b * LEN * EDIM;
    const float* kb = k + (size_t)b * LEN * EDIM;
    float* qTb = qT + (size_t)b * EDIM * LEN;
    float* kTb = kT + (size_t)b * EDIM * LEN;

    #pragma unroll
    for (int i = 0; i < 4; ++i) {
        int row = tr + 16 * i;
        float4 v = *(const float4*)(qb + (size_t)(t0 + row) * EDIM + e0 + 4 * cx);
        tile[4 * cx + 0][row] = v.x;
        tile[4 * cx + 1][row] = v.y;
        tile[4 * cx + 2][row] = v.z;
        tile[4 * cx + 3][row] = v.w;
    }
    __syncthreads();
    #pragma unroll
    for (int i = 0; i < 4; ++i) {
        int seg = tg + 4 * i;
        float4 v = make_float4(tile[er][4 * seg + 0], tile[er][4 * seg + 1],
                               tile[er][4 * seg + 2], tile[er][4 * seg + 3]);
        *(float4*)(qTb + (size_t)(e0 + er) * LEN + t0 + 4 * seg) = v;
    }
    __syncthreads();
    #pragma unroll
    for (int i = 0; i < 4; ++i) {
        int row = tr + 16 * i;
        float4 v = *(const float4*)(kb + (size_t)(t0 + row) * EDIM + e0 + 4 * cx);
        tile[4 * cx + 0][row] = v.x;
        tile[4 * cx + 1][row] = v.y;
        tile[4 * cx + 2][row] = v.z;
        tile[4 * cx + 3][row] = v.w;
    }
    __syncthreads();
    #pragma unroll
    for (int i = 0; i < 4; ++i) {
        int seg = tg + 4 * i;
        float4 v = make_float4(tile[er][4 * seg + 0], tile[er][4 * seg + 1],
                               tile[er][4 * seg + 2], tile[er][4 * seg + 3]);
        *(float4*)(kTb + (size_t)(e0 + er) * LEN + t0 + 4 * seg) = v;
    }
}

// w^p for p=1..7, w = e^{i*ang}. One sincosf + squared chains.
__device__ inline void tw8(float ang, float2* w) {
    float s, c;
    sincosf(ang, &s, &c);
    w[1] = make_float2(c, s);
    w[2] = cmul(w[1], w[1]);
    w[3] = cmul(w[2], w[1]);
    w[4] = cmul(w[2], w[2]);
    w[5] = cmul(w[3], w[2]);
    w[6] = cmul(w[3], w[3]);
    w[7] = cmul(w[4], w[3]);
}

// Forward radix-8 DIF pass.
__device__ inline void fwd8(float2* P, int base, int stride, const float2* w) {
    const float C = 0.70710678118654752f;
    float2 v[8];
    #pragma unroll
    for (int r = 0; r < 8; ++r) v[r] = P[sw(base + stride * r)];
    float2 y0 = cadd(v[0], v[4]), y1 = cadd(v[1], v[5]);
    float2 y2 = cadd(v[2], v[6]), y3 = cadd(v[3], v[7]);
    float2 t0 = csub(v[0], v[4]), t1 = csub(v[1], v[5]);
    float2 t2 = csub(v[2], v[6]), t3 = csub(v[3], v[7]);
    float2 z0 = t0;
    float2 z1 = make_float2(C * (t1.x + t1.y), C * (t1.y - t1.x));   // t1 * (C,-C)
    float2 z2 = make_float2(t2.y, -t2.x);                            // t2 * (0,-1)
    float2 z3 = make_float2(C * (t3.y - t3.x), -C * (t3.x + t3.y));  // t3 * (-C,-C)
    float2 a0 = cadd(y0, y2), a1 = cadd(y1, y3);
    float2 b0 = csub(y0, y2), tb = csub(y1, y3);
    float2 b1 = make_float2(tb.y, -tb.x);
    float2 c0 = cadd(z0, z2), c1 = cadd(z1, z3);
    float2 d0 = csub(z0, z2), td = csub(z1, z3);
    float2 d1 = make_float2(td.y, -td.x);
    float2 X0 = cadd(a0, a1), X4 = csub(a0, a1);
    float2 X2 = cadd(b0, b1), X6 = csub(b0, b1);
    float2 X1 = cadd(c0, c1), X5 = csub(c0, c1);
    float2 X3 = cadd(d0, d1), X7 = csub(d0, d1);
    P[sw(base)]              = X0;
    P[sw(base + stride)]     = cmul(X1, w[1]);
    P[sw(base + 2 * stride)] = cmul(X2, w[2]);
    P[sw(base + 3 * stride)] = cmul(X3, w[3]);
    P[sw(base + 4 * stride)] = cmul(X4, w[4]);
    P[sw(base + 5 * stride)] = cmul(X5, w[5]);
    P[sw(base + 6 * stride)] = cmul(X6, w[6]);
    P[sw(base + 7 * stride)] = cmul(X7, w[7]);
}

// Inverse radix-8 DIT pass (w[] built from +ang).
__device__ inline void inv8(float2* P, int base, int stride, const float2* w) {
    const float C = 0.70710678118654752f;
    float2 v[8];
    #pragma unroll
    for (int p = 0; p < 8; ++p) v[p] = P[sw(base + stride * p)];
    #pragma unroll
    for (int p = 1; p < 8; ++p) v[p] = cmul(v[p], w[p]);
    float2 y0 = cadd(v[0], v[4]), y1 = cadd(v[1], v[5]);
    float2 y2 = cadd(v[2], v[6]), y3 = cadd(v[3], v[7]);
    float2 t0 = csub(v[0], v[4]), t1 = csub(v[1], v[5]);
    float2 t2 = csub(v[2], v[6]), t3 = csub(v[3], v[7]);
    float2 z0 = t0;
    float2 z1 = make_float2(C * (t1.x - t1.y), C * (t1.x + t1.y));   // t1 * (C, C)
    float2 z2 = make_float2(-t2.y, t2.x);                            // t2 * (0, 1)
    float2 z3 = make_float2(-C * (t3.x + t3.y), C * (t3.x - t3.y));  // t3 * (-C, C)
    float2 a0 = cadd(y0, y2), a1 = cadd(y1, y3);
    float2 b0 = csub(y0, y2), tb = csub(y1, y3);
    float2 b1 = make_float2(-tb.y, tb.x);
    float2 c0 = cadd(z0, z2), c1 = cadd(z1, z3);
    float2 d0 = csub(z0, z2), td = csub(z1, z3);
    float2 d1 = make_float2(-td.y, td.x);
    float2 X0 = cadd(a0, a1), X4 = csub(a0, a1);
    float2 X2 = cadd(b0, b1), X6 = csub(b0, b1);
    float2 X1 = cadd(c0, c1), X5 = csub(c0, c1);
    float2 X3 = cadd(d0, d1), X7 = csub(d0, d1);
    P[sw(base)]              = X0;
    P[sw(base + stride)]     = X1;
    P[sw(base + 2 * stride)] = X2;
    P[sw(base + 3 * stride)] = X3;
    P[sw(base + 4 * stride)] = X4;
    P[sw(base + 5 * stride)] = X5;
    P[sw(base + 6 * stride)] = X6;
    P[sw(base + 7 * stride)] = X7;
}

// Radix-4, no twiddle (q=0).
__device__ inline void fwd4(float2* P, int base) {
    float2 v0 = P[sw(base)], v1 = P[sw(base + 1)], v2 = P[sw(base + 2)], v3 = P[sw(base + 3)];
    float2 a0 = cadd(v0, v2), a1 = cadd(v1, v3);
    float2 b0 = csub(v0, v2), t = csub(v1, v3);
    float2 b1 = make_float2(t.y, -t.x);
    P[sw(base)]     = cadd(a0, a1);
    P[sw(base + 2)] = csub(a0, a1);
    P[sw(base + 1)] = cadd(b0, b1);
    P[sw(base + 3)] = csub(b0, b1);
}
__device__ inline void inv4(float2* P, int base) {
    float2 v0 = P[sw(base)], v1 = P[sw(base + 1)], v2 = P[sw(base + 2)], v3 = P[sw(base + 3)];
    float2 a0 = cadd(v0, v2), a1 = cadd(v1, v3);
    float2 b0 = csub(v0, v2), t = csub(v1, v3);
    float2 b1 = make_float2(-t.y, t.x);
    P[sw(base)]     = cadd(a0, a1);
    P[sw(base + 2)] = csub(a0, a1);
    P[sw(base + 1)] = cadd(b0, b1);
    P[sw(base + 3)] = csub(b0, b1);
}

// Storage slot of frequency k after DIF passes radix 8,8,8,4 (digit-reversed).
__device__ inline int slotOf(int k) {
    return ((k & 7) << 8) | (((k >> 3) & 7) << 5) | (((k >> 6) & 7) << 2) | ((k >> 9) & 3);
}

// Packed FFT correlation core (radix-8 register FFT, 4 passes/direction).
__device__ inline void fft_core(float2* A, float2* Bs, int tid) {
    const float PI2 = 6.283185307179586f;
    float2 w[8];
    tw8(-PI2 * (float)tid * (1.0f / 2048.0f), w);
    fwd8(A, tid, 256, w);
    fwd8(Bs, tid, 256, w);
    __syncthreads();
    {
        int c = tid >> 5, q = tid & 31, base = c * 256 + q;
        tw8(-PI2 * (float)q * (1.0f / 256.0f), w);
        fwd8(A, base, 32, w);
        fwd8(Bs, base, 32, w);
    }
    __syncthreads();
    {
        int c = tid >> 2, q = tid & 3, base = c * 32 + q;
        tw8(-PI2 * (float)q * (1.0f / 32.0f), w);
        fwd8(A, base, 4, w);
        fwd8(Bs, base, 4, w);
    }
    __syncthreads();
    fwd4(A, 4 * tid);  fwd4(A, 4 * (tid + 256));
    fwd4(Bs, 4 * tid); fwd4(Bs, 4 * (tid + 256));
    __syncthreads();
    // Pointwise in digit-reversed domain: Hermitian unpack of packed real
    // pair, C = Q*conj(K) per channel, repack W = C0 + i*C1.
    for (int f = tid; f <= 1024; f += 256) {
        int nf = (2048 - f) & 2047;
        int ia = sw(slotOf(f));
        int ib = sw(slotOf(nf));
        float2 z1 = A[ia],  z1n = A[ib];
        float2 z2 = Bs[ia], z2n = Bs[ib];
        float Qx = 0.5f * (z1.x + z1n.x), Qy = 0.5f * (z1.y - z1n.y);
        float Kx = 0.5f * (z1.y + z1n.y), Ky = 0.5f * (z1n.x - z1.x);
        float C1x = Qx * Kx + Qy * Ky;
        float C1y = Qy * Kx - Qx * Ky;
        float Px = 0.5f * (z2.x + z2n.x), Py = 0.5f * (z2.y - z2n.y);
        float Lx = 0.5f * (z2.y + z2n.y), Ly = 0.5f * (z2n.x - z2.x);
        float C2x = Px * Lx + Py * Ly;
        float C2y = Py * Lx - Px * Ly;
        A[ia] = make_float2(C1x - C2y, C1y + C2x);
        if (f != 0 && f != 1024)
            A[ib] = make_float2(C1x + C2y, C2x - C1y);
    }
    __syncthreads();
    inv4(A, 4 * tid); inv4(A, 4 * (tid + 256));
    __syncthreads();
    {
        int c = tid >> 2, q = tid & 3, base = c * 32 + q;
        tw8(PI2 * (float)q * (1.0f / 32.0f), w);
        inv8(A, base, 4, w);
    }
    __syncthreads();
    {
        int c = tid >> 5, q = tid & 31, base = c * 256 + q;
        tw8(PI2 * (float)q * (1.0f / 256.0f), w);
        inv8(A, base, 32, w);
    }
    __syncthreads();
    tw8(PI2 * (float)tid * (1.0f / 2048.0f), w);
    inv8(A, tid, 256, w);
    __syncthreads();
}

// K1 (Path A): two contiguous channel rows per block (from transposed bufs).
// corr may alias qT: rows ch0,ch0+1 fully read into LDS before the store.
__global__ __launch_bounds__(256, 5) void fft_corr(const float* qT,
                                                   const float* kT,
                                                   float* corr) {
    __shared__ float2 A[LEN];
    __shared__ float2 Bs[LEN];
    int ch0 = blockIdx.x * 2;
    int tid = threadIdx.x;
    const float4* q4 = (const float4*)(qT + (size_t)ch0 * LEN);
    const float4* k4 = (const float4*)(kT + (size_t)ch0 * LEN);
    for (int t4 = tid; t4 < LEN / 4; t4 += 256) {
        float4 qa = q4[t4],           ka = k4[t4];
        float4 qb = q4[t4 + LEN / 4], kb = k4[t4 + LEN / 4];
        int t = t4 * 4;
        A[sw(t)]      = make_float2(qa.x, ka.x);
        A[sw(t + 1)]  = make_float2(qa.y, ka.y);
        A[sw(t + 2)]  = make_float2(qa.z, ka.z);
        A[sw(t + 3)]  = make_float2(qa.w, ka.w);
        Bs[sw(t)]     = make_float2(qb.x, kb.x);
        Bs[sw(t + 1)] = make_float2(qb.y, kb.y);
        Bs[sw(t + 2)] = make_float2(qb.z, kb.z);
        Bs[sw(t + 3)] = make_float2(qb.w, kb.w);
    }
    __syncthreads();
    fft_core(A, Bs, tid);
    const float inv = 1.0f / (float)LEN;
    float4* c0 = (float4*)(corr + (size_t)ch0 * LEN);
    float4* c1 = (float4*)(corr + (size_t)(ch0 + 1) * LEN);
    for (int t4 = tid; t4 < LEN / 4; t4 += 256) {
        int t = t4 * 4;
        float2 e0 = A[sw(t)], e1 = A[sw(t + 1)], e2 = A[sw(t + 2)], e3 = A[sw(t + 3)];
        c0[t4] = make_float4(e0.x * inv, e1.x * inv, e2.x * inv, e3.x * inv);
        c1[t4] = make_float4(e0.y * inv, e1.y * inv, e2.y * inv, e3.y * inv);
    }
}

// K1 (Path B): read q,k strided directly from (B,L,E); corr rows chunk-local.
__global__ __launch_bounds__(256, 5) void fft_corr_strided(const float* q,
                                                           const float* k,
                                                           float* corr,
                                                           int chStart) {
    __shared__ float2 A[LEN];
    __shared__ float2 Bs[LEN];
    int chLocal = blockIdx.x * 2;
    int gch = chStart + chLocal;
    int b   = gch >> 9;           // / EDIM
    int e   = gch & (EDIM - 1);   // even (HD per head, paired)
    int tid = threadIdx.x;
    const float* qr = q + (size_t)b * LEN * EDIM + e;
    const float* kr = k + (size_t)b * LEN * EDIM + e;
    for (int t = tid; t < LEN; t += 256) {
        float2 qv = *(const float2*)(qr + (size_t)t * EDIM);
        float2 kv = *(const float2*)(kr + (size_t)t * EDIM);
        A[sw(t)]  = make_float2(qv.x, kv.x);
        Bs[sw(t)] = make_float2(qv.y, kv.y);
    }
    __syncthreads();
    fft_core(A, Bs, tid);
    const float inv = 1.0f / (float)LEN;
    float4* c0 = (float4*)(corr + (size_t)chLocal * LEN);
    float4* c1 = (float4*)(corr + (size_t)(chLocal + 1) * LEN);
    for (int t4 = tid; t4 < LEN / 4; t4 += 256) {
        int t = t4 * 4;
        float2 e0 = A[sw(t)], e1 = A[sw(t + 1)], e2 = A[sw(t + 2)], e3 = A[sw(t + 3)];
        c0[t4] = make_float4(e0.x * inv, e1.x * inv, e2.x * inv, e3.x * inv);
        c1[t4] = make_float4(e0.y * inv, e1.y * inv, e2.y * inv, e3.y * inv);
    }
}

// K2: per (b,h,l): top-7 over 64 channel-scores, softmax, gather-weighted sum.
// KEY: delays are channel indices, so dk in [0,64) -> gather window is rows
// [l-63, l]. A 128-l block needs only 192 V-rows (48 KB): stage them in LDS
// once (coalesced float4), then all 7-way gathers are conflict-free LDS reads
// (vtile[r][lane], bank = lane&31, 2-way = free) with r = lp - dk + 64.
__global__ __launch_bounds__(256, 2) void topk_agg(const float* __restrict__ corr,
                                                   const float* __restrict__ values,
                                                   float* __restrict__ out,
                                                   int bhBase) {
    __shared__ float  vtile[VROWS][HD];   // 48 KB
    __shared__ float2 w_d[LBLK][TOPK];    // 7 KB
    int l0 = blockIdx.x * LBLK;
    int lh = blockIdx.y;            // local head index within chunk
    int bh = bhBase + lh;
    int b  = bh >> 3;
    int h  = bh & 7;
    int tid = threadIdx.x;
    const float* vb0 = values + (size_t)b * LEN * EDIM + h * HD;

    // ---- stage V window rows (l0-64 .. l0+127), wrapped mod LEN
    for (int idx = tid; idx < VROWS * (HD / 4); idx += 256) {
        int r  = idx >> 4;
        int c4 = idx & 15;
        int gr = (l0 - 64 + r) & (LEN - 1);
        float4 v = *(const float4*)(vb0 + (size_t)gr * EDIM + 4 * c4);
        *(float4*)&vtile[r][4 * c4] = v;
    }

    // ---- phase 1: per-thread top-7 over the 64 channels of row l = l0+tid
    if (tid < LBLK) {
        const float* cb = corr + (size_t)lh * HD * LEN + l0 + tid;
        float wk[TOPK];
        int   dk[TOPK];
        #pragma unroll
        for (int t = 0; t < TOPK; ++t) { wk[t] = -INFINITY; dk[t] = 0; }
        #pragma unroll 8
        for (int c = 0; c < HD; ++c) {
            float nv = cb[(size_t)c * LEN];
            int   nd = c;
            #pragma unroll
            for (int t = 0; t < TOPK; ++t) {   // stable: strict > keeps low index first
                bool  m  = nv > wk[t];
                float tv = wk[t]; int td = dk[t];
                wk[t] = m ? nv : tv;
                dk[t] = m ? nd : td;
                nv    = m ? tv : nv;
                nd    = m ? td : nd;
            }
        }
        float mx = wk[0], sum = 0.f;
        float e[TOPK];
        #pragma unroll
        for (int t = 0; t < TOPK; ++t) { e[t] = expf(wk[t] - mx); sum += e[t]; }
        float invs = 1.f / sum;
        #pragma unroll
        for (int t = 0; t < TOPK; ++t)
            w_d[tid][t] = make_float2(e[t] * invs, __int_as_float(dk[t]));
    }
    __syncthreads();

    // ---- phase 2: gather from LDS. lane = channel, each wave covers 32 l.
    int lane = tid & 63;
    int wave = tid >> 6;
    float* ob = out + (size_t)b * LEN * EDIM + h * HD + lane;
    for (int i = 0; i < LBLK / 4; ++i) {
        int lp = wave * (LBLK / 4) + i;
        int l  = l0 + lp;
        float acc = 0.f;
        #pragma unroll
        for (int t = 0; t < TOPK; ++t) {
            float2 wd = w_d[lp][t];     // wave-uniform -> LDS broadcast
            int r = lp - __float_as_int(wd.y) + 64;   // in [1, 191]
            acc += wd.x * vtile[r][lane];
        }
        ob[(size_t)l * EDIM] = acc;
    }
}

extern "C" void kernel_launch(void* const* d_in, const int* in_sizes, int n_in,
                              void* d_out, int out_size, void* d_ws, size_t ws_size,
                              hipStream_t stream) {
    const float* q = (const float*)d_in[0];
    const float* k = (const float*)d_in[1];
    const float* v = (const float*)d_in[2];
    float* out = (float*)d_out;

    const size_t CORR_BYTES = (size_t)NB * EDIM * LEN * sizeof(float);  // 64 MB

    if (ws_size >= CORR_BYTES) {
        // Path A: qT in ws; kT staged in d_out (dead until topk rewrites it);
        // corr aliases qT (row-consistent aliasing: each fft block reads its
        // own rows fully into LDS before storing them).
        float* qT   = (float*)d_ws;
        float* kT   = (float*)d_out;
        float* corr = qT;
        transpose_qk<<<dim3(EDIM / 64, LEN / 64, NB), dim3(256), 0, stream>>>(q, k, qT, kT);
        fft_corr<<<dim3(NB * EDIM / 2), dim3(256), 0, stream>>>(qT, kT, corr);
        topk_agg<<<dim3(LEN / LBLK, NB * NH), dim3(256), 0, stream>>>(corr, v, out, 0);
    } else {
        // Path B: chunk by heads; corr chunk lives in ws (512 KB per head).
        const size_t HEAD_BYTES = (size_t)HD * LEN * sizeof(float);
        int headsPer = (int)(ws_size / HEAD_BYTES);
        if (headsPer < 1) headsPer = 1;
        if (headsPer > NB * NH) headsPer = NB * NH;
        float* corr = (float*)d_ws;
        for (int hs = 0; hs < NB * NH; hs += headsPer) {
            int hc = NB * NH - hs < headsPer ? NB * NH - hs : headsPer;
            fft_corr_strided<<<dim3(hc * HD / 2), dim3(256), 0, stream>>>(q, k, corr, hs * HD);
            topk_agg<<<dim3(LEN / LBLK, hc), dim3(256), 0, stream>>>(corr, v, out, hs);
        }
    }
}